// Round 5
// baseline (357.648 us; speedup 1.0000x reference)
//
#include <hip/hip_runtime.h>
#include <math.h>

#define BATCH 8
#define CHAN 256
#define HH 128
#define WW 128
#define NMASK 100
#define HWSZ (HH*WW)
#define KD 128

// d_out layout: [logits 800][kernel 102400][scores 800][iam 13107200]
#define OFF_LOGITS 0
#define OFF_KERNEL 800
#define OFF_SCORES (800 + 800*KD)
#define OFF_IAM    (OFF_SCORES + 800)

typedef __attribute__((ext_vector_type(8))) short bf16x8;
typedef __attribute__((ext_vector_type(8))) unsigned short ushort8;
typedef __attribute__((ext_vector_type(4))) float f32x4;

__device__ __forceinline__ unsigned short f2bf(float f){
  unsigned int u = __float_as_uint(f);
  u += 0x7fffu + ((u >> 16) & 1u);
  return (unsigned short)(u >> 16);
}

// ---------------- weight pre-pack into A-fragment order ----------------
__global__ __launch_bounds__(256) void wpack_kernel(
    const float* __restrict__ cw, unsigned short* __restrict__ wr)
{
  int i = blockIdx.x*256 + threadIdx.x;
  if (i >= 9*8*7*64*8) return;
  int j = i & 7;
  int l = (i >> 3) & 63;
  int rest = i >> 9;
  int nt = rest % 7;
  int cc8 = rest / 7;
  int cc = cc8 & 7;
  int tap = cc8 >> 3;
  int n = nt*16 + (l & 15);
  int c = cc*32 + (l >> 4)*8 + j;
  float v = 0.f;
  if (n < NMASK) v = cw[((size_t)n*CHAN + c)*9 + tap];
  wr[i] = f2bf(v);
}

// ---------------- feature layout prepass: fp32 [b][c][p] -> bf16 [b][cg][p][c8] ----
// grid (8 p-tiles, 32 cg, 8 b), 256 thr. LDS-tiled transpose, 8 subtiles of 256 p.
__global__ __launch_bounds__(256) void prepack_feat_kernel(
    const float* __restrict__ feat, unsigned short* __restrict__ feath)
{
  const int b  = blockIdx.z;
  const int cg = blockIdx.y;
  const int t  = threadIdx.x;
  __shared__ unsigned short lt[8*264];
  const int cl = t >> 5;           // 0..7
  const int po = (t & 31)*8;       // 0..248
  for (int st=0; st<8; ++st){
    const int P0 = blockIdx.x*2048 + st*256;
    const float* src = feat + ((size_t)(b*CHAN + cg*8 + cl))*HWSZ + P0 + po;
    float4 a0 = *(const float4*)src;
    float4 a1 = *(const float4*)(src+4);
    ushort8 u;
    u[0]=f2bf(a0.x); u[1]=f2bf(a0.y); u[2]=f2bf(a0.z); u[3]=f2bf(a0.w);
    u[4]=f2bf(a1.x); u[5]=f2bf(a1.y); u[6]=f2bf(a1.z); u[7]=f2bf(a1.w);
    *(ushort8*)&lt[cl*264 + po] = u;
    __syncthreads();
    ushort8 v;
    #pragma unroll
    for (int c=0;c<8;c++) v[c] = lt[c*264 + t];
    *(ushort8*)&feath[(((size_t)b*32 + cg)*HWSZ + P0 + t)*8] = v;
    __syncthreads();
  }
}

// ---------------- conv v2: implicit-GEMM MFMA, bf16 staged from feat_h ----------
#define LDSX 40
__global__ __launch_bounds__(256) void conv_mfma2_kernel(
    const unsigned short* __restrict__ feath, const unsigned short* __restrict__ wr,
    const float* __restrict__ cb, float* __restrict__ out_iam)
{
  const int h = blockIdx.x;
  const int b = blockIdx.y;
  const int t = threadIdx.x;
  const int w = t >> 6;
  const int l = t & 63;
  const int lx = l & 15;
  const int lg = l >> 4;
  const int x  = t & 127;      // staging x (fixed per thread)
  const int pr = t >> 7;       // staging parity

  __shared__ unsigned short lds[3*132*LDSX];

  // zero halo columns (xh=0,129) for all rows; zero whole invalid boundary rows
  for (int e=t; e<3*2*LDSX; e+=256){
    int kh = e/(2*LDSX); int rem = e - kh*2*LDSX; int side = rem/LDSX; int c = rem - side*LDSX;
    lds[(kh*132 + (side?129:0))*LDSX + c] = 0;
  }
  if (h==0)   for (int e=t; e<132*LDSX; e+=256) lds[e] = 0;
  if (h==127) for (int e=t; e<132*LDSX; e+=256) lds[2*132*LDSX + e] = 0;

  f32x4 acc[7][2];
  #pragma unroll
  for (int nt=0;nt<7;nt++)
    #pragma unroll
    for (int pi=0;pi<2;pi++) acc[nt][pi] = (f32x4){0.f,0.f,0.f,0.f};

  const unsigned short* fb = feath + (size_t)b*32*HWSZ*8;

  ushort8 rs[6];
  // stage_load(cc): 6x 16B coalesced loads into regs (i static: kh=i>>1, cg=pr+2*(i&1))
  #define STAGE_LOAD(cc) { \
    _Pragma("unroll") \
    for (int i=0;i<6;i++){ \
      const int kh = i>>1; \
      const int cg = pr + 2*(i&1); \
      const int row = h + kh - 1; \
      if ((unsigned)row < 128u) \
        rs[i] = *(const ushort8*)&fb[(((size_t)(cc)*4 + cg)*HWSZ + row*WW + x)*8]; \
    } }
  #define STAGE_WRITE() { \
    _Pragma("unroll") \
    for (int i=0;i<6;i++){ \
      const int kh = i>>1; \
      const int cg = pr + 2*(i&1); \
      const int row = h + kh - 1; \
      if ((unsigned)row < 128u) \
        *(ushort8*)&lds[((kh*132) + x + 1)*LDSX + cg*8] = rs[i]; \
    } }

  STAGE_LOAD(0);
  STAGE_WRITE();
  __syncthreads();

  for (int cc=0; cc<8; ++cc){
    if (cc < 7) STAGE_LOAD(cc+1);      // async: latency hides under MFMAs

    const unsigned short* wbase = wr + ((size_t)cc*7*64 + l)*8;
    #pragma unroll 1
    for (int tap=0; tap<9; ++tap){
      const int kh = tap / 3;
      const int kw = tap - kh*3;
      bf16x8 a[7];
      #pragma unroll
      for (int nt=0; nt<7; nt++)
        a[nt] = *(const bf16x8*)(wbase + ((size_t)tap*8*7 + nt)*64*8);
      bf16x8 bfv[2];
      #pragma unroll
      for (int pi=0; pi<2; pi++){
        int xh = (w*2+pi)*16 + lx + kw;
        bfv[pi] = *(const bf16x8*)&lds[(kh*132 + xh)*LDSX + lg*8];
      }
      #pragma unroll
      for (int nt=0; nt<7; nt++)
        #pragma unroll
        for (int pi=0; pi<2; pi++)
          acc[nt][pi] = __builtin_amdgcn_mfma_f32_16x16x32_bf16(
              a[nt], bfv[pi], acc[nt][pi], 0, 0, 0);
    }
    __syncthreads();                   // all waves done reading lds
    if (cc < 7){
      STAGE_WRITE();                   // write next chunk
      __syncthreads();
    }
  }

  #pragma unroll
  for (int nt=0; nt<7; nt++){
    const int n0 = nt*16 + lg*4;
    #pragma unroll
    for (int pi=0; pi<2; pi++){
      const int xo = (w*2+pi)*16 + lx;
      #pragma unroll
      for (int r=0; r<4; r++){
        int n = n0 + r;
        if (n < NMASK)
          out_iam[((size_t)b*NMASK + n)*HWSZ + h*WW + xo] = acc[nt][pi][r] + cb[n];
      }
    }
  }
}

// ---------------- conv v1 (fallback, fp32 staging) ----------------
__global__ __launch_bounds__(256) void conv_mfma_kernel(
    const float* __restrict__ feat, const unsigned short* __restrict__ wr,
    const float* __restrict__ cb, float* __restrict__ out_iam)
{
  const int h = blockIdx.x;
  const int b = blockIdx.y;
  const int t = threadIdx.x;
  const int w = t >> 6;
  const int l = t & 63;
  const int lx = l & 15;
  const int lg = l >> 4;

  __shared__ unsigned short lds[3*132*LDSX];

  f32x4 acc[7][2];
  #pragma unroll
  for (int nt=0;nt<7;nt++)
    #pragma unroll
    for (int pi=0;pi<2;pi++) acc[nt][pi] = (f32x4){0.f,0.f,0.f,0.f};

  const float* fb = feat + (size_t)b*CHAN*HWSZ;

  for (int cc=0; cc<8; ++cc){
    const int c0 = cc*32;
    __syncthreads();
    for (int gi = t; gi < 1560; gi += 256){
      int xh = gi % 130;
      int q  = gi / 130;
      int cg = q & 3;
      int kh = q >> 2;
      int row = h + kh - 1;
      int xx  = xh - 1;
      bool ok = ((unsigned)row < 128u) & ((unsigned)xx < 128u);
      const float* src = fb + (size_t)(c0 + cg*8)*HWSZ + row*WW + xx;
      ushort8 u;
      #pragma unroll
      for (int j=0;j<8;j++){
        float v = ok ? src[(size_t)j*HWSZ] : 0.f;
        u[j] = f2bf(v);
      }
      *(ushort8*)&lds[(kh*132 + xh)*LDSX + cg*8] = u;
    }
    __syncthreads();

    const unsigned short* wbase = wr + ((size_t)cc*7*64 + l)*8;
    #pragma unroll 1
    for (int tap=0; tap<9; ++tap){
      const int kh = tap / 3;
      const int kw = tap - kh*3;
      bf16x8 a[7];
      #pragma unroll
      for (int nt=0; nt<7; nt++)
        a[nt] = *(const bf16x8*)(wbase + ((size_t)tap*8*7 + nt)*64*8);
      bf16x8 bfv[2];
      #pragma unroll
      for (int pi=0; pi<2; pi++){
        int xh = (w*2+pi)*16 + lx + kw;
        bfv[pi] = *(const bf16x8*)&lds[(kh*132 + xh)*LDSX + lg*8];
      }
      #pragma unroll
      for (int nt=0; nt<7; nt++)
        #pragma unroll
        for (int pi=0; pi<2; pi++)
          acc[nt][pi] = __builtin_amdgcn_mfma_f32_16x16x32_bf16(
              a[nt], bfv[pi], acc[nt][pi], 0, 0, 0);
    }
  }

  #pragma unroll
  for (int nt=0; nt<7; nt++){
    const int n0 = nt*16 + lg*4;
    #pragma unroll
    for (int pi=0; pi<2; pi++){
      const int xo = (w*2+pi)*16 + lx;
      #pragma unroll
      for (int r=0; r<4; r++){
        int n = n0 + r;
        if (n < NMASK)
          out_iam[((size_t)b*NMASK + n)*HWSZ + h*WW + xo] = acc[nt][pi][r] + cb[n];
      }
    }
  }
}

// ---------------- softmax row stats (max, 1/sumexp) ----------------
__global__ __launch_bounds__(256) void softmax_stats_kernel(
    const float* __restrict__ iam, float* __restrict__ rowmax, float* __restrict__ rowinv)
{
  const int row = blockIdx.x;
  const int t = threadIdx.x;
  const float* p = iam + (size_t)row*HWSZ;
  __shared__ float red[256];
  float m = -1e30f;
  for (int it=0; it<16; it++){
    float4 v = *(const float4*)&p[(it*256+t)*4];
    m = fmaxf(m, fmaxf(fmaxf(v.x,v.y), fmaxf(v.z,v.w)));
  }
  red[t] = m; __syncthreads();
  for (int s=128;s>0;s>>=1){ if (t<s) red[t]=fmaxf(red[t],red[t+s]); __syncthreads(); }
  m = red[0]; __syncthreads();
  float sum=0.f;
  for (int it=0; it<16; it++){
    float4 v = *(const float4*)&p[(it*256+t)*4];
    sum += expf(v.x-m)+expf(v.y-m)+expf(v.z-m)+expf(v.w-m);
  }
  red[t]=sum; __syncthreads();
  for (int s=128;s>0;s>>=1){ if (t<s) red[t]+=red[t+s]; __syncthreads(); }
  if (t==0){ rowmax[row]=m; rowinv[row]=1.0f/red[0]; }
}

// ---------------- einsum as MFMA (no LDS, no barriers) ----------------
__global__ __launch_bounds__(256) void einsum_mfma_kernel(
  const float* __restrict__ feat, const float* __restrict__ iam,
  const float* __restrict__ rowmax, const float* __restrict__ rowinv,
  float* __restrict__ partial)
{
  const int s = blockIdx.x;
  const int nsplit = gridDim.x;
  const int KC = HWSZ / nsplit;
  const int b = blockIdx.z;
  const int t = threadIdx.x;
  const int w = t >> 6;
  const int l = t & 63;
  const int lx = l & 15;
  const int lg = l >> 4;

  f32x4 acc[7][4];
  #pragma unroll
  for (int nt=0;nt<7;nt++)
    #pragma unroll
    for (int j=0;j<4;j++) acc[nt][j] = (f32x4){0.f,0.f,0.f,0.f};

  int   rown[7];
  float m_[7], r_[7];
  #pragma unroll
  for (int nt=0;nt<7;nt++){
    int row = nt*16 + lx;
    if (row >= NMASK) row = NMASK-1;
    rown[nt] = row;
    m_[nt] = rowmax[b*NMASK + row];
    r_[nt] = rowinv[b*NMASK + row];
  }

  const float* fb = feat + (size_t)b*CHAN*HWSZ;
  const float* ib = iam  + (size_t)b*NMASK*HWSZ;

  #pragma unroll 1
  for (int ks=0; ks<KC/32; ++ks){
    const int p0 = s*KC + ks*32 + lg*8;
    bf16x8 afr[7];
    #pragma unroll
    for (int nt=0;nt<7;nt++){
      const float* ap = ib + (size_t)rown[nt]*HWSZ + p0;
      float4 a0 = *(const float4*)ap;
      float4 a1 = *(const float4*)(ap+4);
      const float m = m_[nt], rv = r_[nt];
      ushort8 u;
      u[0]=f2bf(__expf(a0.x-m)*rv); u[1]=f2bf(__expf(a0.y-m)*rv);
      u[2]=f2bf(__expf(a0.z-m)*rv); u[3]=f2bf(__expf(a0.w-m)*rv);
      u[4]=f2bf(__expf(a1.x-m)*rv); u[5]=f2bf(__expf(a1.y-m)*rv);
      u[6]=f2bf(__expf(a1.z-m)*rv); u[7]=f2bf(__expf(a1.w-m)*rv);
      afr[nt] = *(bf16x8*)&u;
    }
    bf16x8 bfr[4];
    #pragma unroll
    for (int j=0;j<4;j++){
      const float* fp = fb + (size_t)(w*64 + j*16 + lx)*HWSZ + p0;
      float4 b0 = *(const float4*)fp;
      float4 b1 = *(const float4*)(fp+4);
      ushort8 u;
      u[0]=f2bf(b0.x); u[1]=f2bf(b0.y); u[2]=f2bf(b0.z); u[3]=f2bf(b0.w);
      u[4]=f2bf(b1.x); u[5]=f2bf(b1.y); u[6]=f2bf(b1.z); u[7]=f2bf(b1.w);
      bfr[j] = *(bf16x8*)&u;
    }
    #pragma unroll
    for (int nt=0;nt<7;nt++)
      #pragma unroll
      for (int j=0;j<4;j++)
        acc[nt][j] = __builtin_amdgcn_mfma_f32_16x16x32_bf16(
            afr[nt], bfr[j], acc[nt][j], 0, 0, 0);
  }

  #pragma unroll
  for (int nt=0;nt<7;nt++){
    #pragma unroll
    for (int j=0;j<4;j++){
      const int c = w*64 + j*16 + lx;
      #pragma unroll
      for (int r=0;r<4;r++){
        int n = nt*16 + lg*4 + r;
        if (n < NMASK)
          partial[(((size_t)b*nsplit + s)*NMASK + n)*CHAN + c] = acc[nt][j][r];
      }
    }
  }
}

// ---------------- reduce partials + fc + heads ----------------
__global__ __launch_bounds__(256) void fc_head_kernel(
  const float* __restrict__ partial, int nsplit,
  const float* __restrict__ fc_w, const float* __restrict__ fc_b,
  const float* __restrict__ cls_w, const float* __restrict__ cls_b,
  const float* __restrict__ mk_w, const float* __restrict__ mk_b,
  const float* __restrict__ obj_w, const float* __restrict__ obj_b,
  float* __restrict__ dout)
{
  const int n = blockIdx.x;
  const int b = blockIdx.y;
  const int t = threadIdx.x;
  __shared__ float xs[256];
  __shared__ float xr[256];
  __shared__ float red[256];
  float x = 0.f;
  for (int s=0;s<nsplit;s++)
    x += partial[(((size_t)b*nsplit+s)*NMASK + n)*CHAN + t];
  xs[t] = x;
  __syncthreads();
  float y = fc_b[t];
  const float* wr2 = fc_w + (size_t)t*CHAN;
  for (int k=0;k<CHAN;k+=4){
    float4 w4 = *(const float4*)&wr2[k];
    y = fmaf(xs[k],w4.x,y); y=fmaf(xs[k+1],w4.y,y);
    y = fmaf(xs[k+2],w4.z,y); y=fmaf(xs[k+3],w4.w,y);
  }
  y = fmaxf(y, 0.f);
  xr[t] = y;
  __syncthreads();
  if (t < KD){
    float ka = mk_b[t];
    const float* mr = mk_w + (size_t)t*CHAN;
    for (int k=0;k<CHAN;k+=4){
      float4 w4 = *(const float4*)&mr[k];
      ka = fmaf(xr[k],w4.x,ka); ka=fmaf(xr[k+1],w4.y,ka);
      ka = fmaf(xr[k+2],w4.z,ka); ka=fmaf(xr[k+3],w4.w,ka);
    }
    dout[OFF_KERNEL + ((size_t)b*NMASK + n)*KD + t] = ka;
  }
  red[t] = xr[t] * cls_w[t];
  __syncthreads();
  for (int s2=128;s2>0;s2>>=1){ if(t<s2) red[t]+=red[t+s2]; __syncthreads(); }
  if (t==0) dout[OFF_LOGITS + (size_t)b*NMASK + n] = red[0] + cls_b[0];
  __syncthreads();
  red[t] = xr[t] * obj_w[t];
  __syncthreads();
  for (int s2=128;s2>0;s2>>=1){ if(t<s2) red[t]+=red[t+s2]; __syncthreads(); }
  if (t==0) dout[OFF_SCORES + (size_t)b*NMASK + n] = red[0] + obj_b[0];
}

extern "C" void kernel_launch(void* const* d_in, const int* in_sizes, int n_in,
                              void* d_out, int out_size, void* d_ws, size_t ws_size,
                              hipStream_t stream)
{
  const float* feat   = (const float*)d_in[0];
  const float* conv_w = (const float*)d_in[1];
  const float* conv_b = (const float*)d_in[2];
  // d_in[3] = softmax_bias: scalar shift, softmax-invariant -> unused
  const float* fc_w   = (const float*)d_in[4];
  const float* fc_b   = (const float*)d_in[5];
  const float* cls_w  = (const float*)d_in[6];
  const float* cls_b  = (const float*)d_in[7];
  const float* mk_w   = (const float*)d_in[8];
  const float* mk_b   = (const float*)d_in[9];
  const float* obj_w  = (const float*)d_in[10];
  const float* obj_b  = (const float*)d_in[11];
  float* dout = (float*)d_out;
  float* iam  = dout + OFF_IAM;

  const size_t statb = 1600*sizeof(float);                 // 6400
  const size_t wrb   = (size_t)9*8*7*64*8*2;               // 516096
  const size_t feathb = (size_t)BATCH*32*HWSZ*8*2;         // 67,108,864

  float* rowmax  = (float*)d_ws;
  float* rowinv  = rowmax + 800;
  unsigned short* wr = (unsigned short*)((char*)d_ws + statb);
  char* shared_region = (char*)d_ws + statb + wrb;

  wpack_kernel<<<dim3((9*8*7*64*8 + 255)/256), 256, 0, stream>>>(conv_w, wr);

  if (ws_size >= statb + wrb + feathb + 1024){
    // mode A: prepass + fast conv; partial aliases feat_h (disjoint lifetimes)
    unsigned short* feath = (unsigned short*)shared_region;
    float* partial = (float*)shared_region;
    const int ksplit = 64;   // 52.4 MB < 67.1 MB feat_h region
    prepack_feat_kernel<<<dim3(8,32,8), 256, 0, stream>>>(feat, feath);
    conv_mfma2_kernel<<<dim3(128, 8), 256, 0, stream>>>(feath, wr, conv_b, iam);
    softmax_stats_kernel<<<dim3(800), 256, 0, stream>>>(iam, rowmax, rowinv);
    einsum_mfma_kernel<<<dim3(ksplit, 1, 8), 256, 0, stream>>>(feat, iam, rowmax, rowinv, partial);
    fc_head_kernel<<<dim3(NMASK,BATCH), 256, 0, stream>>>(partial, ksplit, fc_w, fc_b,
        cls_w, cls_b, mk_w, mk_b, obj_w, obj_b, dout);
  } else {
    // mode B: round-4 path (no prepass)
    float* partial = (float*)shared_region;
    int ksplit = 16;
    if (ws_size >= statb + wrb + (size_t)64*BATCH*NMASK*CHAN*4) ksplit = 64;
    else if (ws_size >= statb + wrb + (size_t)32*BATCH*NMASK*CHAN*4) ksplit = 32;
    conv_mfma_kernel<<<dim3(128, 8), 256, 0, stream>>>(feat, wr, conv_b, iam);
    softmax_stats_kernel<<<dim3(800), 256, 0, stream>>>(iam, rowmax, rowinv);
    einsum_mfma_kernel<<<dim3(ksplit, 1, 8), 256, 0, stream>>>(feat, iam, rowmax, rowinv, partial);
    fc_head_kernel<<<dim3(NMASK,BATCH), 256, 0, stream>>>(partial, ksplit, fc_w, fc_b,
        cls_w, cls_b, mk_w, mk_b, obj_w, obj_b, dout);
  }
}

// Round 6
// 267.685 us; speedup vs baseline: 1.3361x; 1.3361x over previous
//
#include <hip/hip_runtime.h>
#include <math.h>

#define BATCH 8
#define CHAN 256
#define HH 128
#define WW 128
#define NMASK 100
#define HWSZ (HH*WW)
#define KD 128

// d_out layout: [logits 800][kernel 102400][scores 800][iam 13107200]
#define OFF_LOGITS 0
#define OFF_KERNEL 800
#define OFF_SCORES (800 + 800*KD)
#define OFF_IAM    (OFF_SCORES + 800)

typedef __attribute__((ext_vector_type(8))) short bf16x8;
typedef __attribute__((ext_vector_type(8))) unsigned short ushort8;
typedef __attribute__((ext_vector_type(4))) float f32x4;

__device__ __forceinline__ unsigned short f2bf(float f){
  unsigned int u = __float_as_uint(f);
  u += 0x7fffu + ((u >> 16) & 1u);
  return (unsigned short)(u >> 16);
}

// ---------------- weight pre-pack into A-fragment order ----------------
// wr[(((tap*8+cc)*7+nt)*64+l)*8+j] = bf16(W[n][c][kh][kw])
__global__ __launch_bounds__(256) void wpack_kernel(
    const float* __restrict__ cw, unsigned short* __restrict__ wr)
{
  int i = blockIdx.x*256 + threadIdx.x;
  if (i >= 9*8*7*64*8) return;
  int j = i & 7;
  int l = (i >> 3) & 63;
  int rest = i >> 9;
  int nt = rest % 7;
  int cc8 = rest / 7;
  int cc = cc8 & 7;
  int tap = cc8 >> 3;
  int n = nt*16 + (l & 15);
  int c = cc*32 + (l >> 4)*8 + j;
  float v = 0.f;
  if (n < NMASK) v = cw[((size_t)n*CHAN + c)*9 + tap];
  wr[i] = f2bf(v);
}

// ---------------- feature layout prepass: fp32 [b][c][p] -> bf16 [b][cg][p][c8] ----
__global__ __launch_bounds__(256) void prepack_feat_kernel(
    const float* __restrict__ feat, unsigned short* __restrict__ feath)
{
  const int b  = blockIdx.z;
  const int cg = blockIdx.y;
  const int t  = threadIdx.x;
  __shared__ unsigned short lt[8*264];
  const int cl = t >> 5;           // 0..7
  const int po = (t & 31)*8;       // 0..248
  for (int st=0; st<8; ++st){
    const int P0 = blockIdx.x*2048 + st*256;
    const float* src = feat + ((size_t)(b*CHAN + cg*8 + cl))*HWSZ + P0 + po;
    float4 a0 = *(const float4*)src;
    float4 a1 = *(const float4*)(src+4);
    ushort8 u;
    u[0]=f2bf(a0.x); u[1]=f2bf(a0.y); u[2]=f2bf(a0.z); u[3]=f2bf(a0.w);
    u[4]=f2bf(a1.x); u[5]=f2bf(a1.y); u[6]=f2bf(a1.z); u[7]=f2bf(a1.w);
    *(ushort8*)&lt[cl*264 + po] = u;
    __syncthreads();
    ushort8 v;
    #pragma unroll
    for (int c=0;c<8;c++) v[c] = lt[c*264 + t];
    *(ushort8*)&feath[(((size_t)b*32 + cg)*HWSZ + P0 + t)*8] = v;
    __syncthreads();
  }
}

// ---------------- conv v3: no-LDS, no-barrier implicit-GEMM MFMA ----------------
// grid (64 h-pairs, 8 b), 4 waves. Wave w owns x-tiles {2w,2w+1} x 2 rows x 7 nt.
// B-frags loaded directly from feath (16B/lane, coalesced); halo = clamp+select.
__global__ __launch_bounds__(256,2) void conv_mfma3_kernel(
    const unsigned short* __restrict__ feath, const unsigned short* __restrict__ wr,
    const float* __restrict__ cb, float* __restrict__ out_iam)
{
  const int h0 = blockIdx.x*2;
  const int b  = blockIdx.y;
  const int t  = threadIdx.x;
  const int w  = t >> 6;
  const int l  = t & 63;
  const int lx = l & 15;
  const int lg = l >> 4;

  f32x4 acc[7][2][2];   // [nt][row][pi]
  #pragma unroll
  for (int nt=0;nt<7;nt++)
    #pragma unroll
    for (int r=0;r<2;r++)
      #pragma unroll
      for (int pi=0;pi<2;pi++) acc[nt][r][pi] = (f32x4){0.f,0.f,0.f,0.f};

  // lane's channel-group base: cg = cc*4 + lg
  const unsigned short* fb = feath + ((size_t)b*32 + lg)*HWSZ*8;
  const unsigned short* wl = wr + (size_t)l*8;
  const int xb0 = (w*2+0)*16 + lx - 1;
  const int xb1 = (w*2+1)*16 + lx - 1;

  #pragma unroll 1
  for (int cc=0; cc<8; ++cc){
    const unsigned short* fcc = fb + (size_t)cc*4*HWSZ*8;
    #pragma unroll
    for (int tap=0; tap<9; ++tap){
      const int kh = tap/3, kw = tap - 3*(tap/3);
      bf16x8 a[7];
      #pragma unroll
      for (int nt=0;nt<7;nt++)
        a[nt] = *(const bf16x8*)(wl + (((size_t)tap*8+cc)*7+nt)*64*8);
      bf16x8 bv[2][2];
      #pragma unroll
      for (int r=0;r<2;r++){
        const int hr = h0 + r + kh - 1;
        const bool rv = (unsigned)hr < 128u;
        const int hc = rv ? hr : 0;
        #pragma unroll
        for (int pi=0;pi<2;pi++){
          const int X = (pi ? xb1 : xb0) + kw;
          const bool xv = (unsigned)X < 128u;
          const int Xc = xv ? X : 0;
          bf16x8 v = *(const bf16x8*)&fcc[((size_t)hc*WW + Xc)*8];
          bv[r][pi] = (rv && xv) ? v : (bf16x8)(short)0;
        }
      }
      #pragma unroll
      for (int nt=0;nt<7;nt++)
        #pragma unroll
        for (int r=0;r<2;r++)
          #pragma unroll
          for (int pi=0;pi<2;pi++)
            acc[nt][r][pi] = __builtin_amdgcn_mfma_f32_16x16x32_bf16(
                a[nt], bv[r][pi], acc[nt][r][pi], 0, 0, 0);
    }
  }

  // D: col(x) = lane&15, row(mask) = (lane>>4)*4 + q
  #pragma unroll
  for (int nt=0; nt<7; nt++){
    const int n0 = nt*16 + lg*4;
    #pragma unroll
    for (int r=0; r<2; r++){
      #pragma unroll
      for (int pi=0; pi<2; pi++){
        const int xo = (w*2+pi)*16 + lx;
        #pragma unroll
        for (int q=0; q<4; q++){
          int n = n0 + q;
          if (n < NMASK)
            out_iam[((size_t)b*NMASK + n)*HWSZ + (h0+r)*WW + xo] = acc[nt][r][pi][q] + cb[n];
        }
      }
    }
  }
}

// ---------------- conv v1 (fallback for small ws: fp32 staging via LDS) ----------
#define LDSX 40
__global__ __launch_bounds__(256) void conv_mfma_kernel(
    const float* __restrict__ feat, const unsigned short* __restrict__ wr,
    const float* __restrict__ cb, float* __restrict__ out_iam)
{
  const int h = blockIdx.x;
  const int b = blockIdx.y;
  const int t = threadIdx.x;
  const int w = t >> 6;
  const int l = t & 63;
  const int lx = l & 15;
  const int lg = l >> 4;

  __shared__ unsigned short lds[3*132*LDSX];

  f32x4 acc[7][2];
  #pragma unroll
  for (int nt=0;nt<7;nt++)
    #pragma unroll
    for (int pi=0;pi<2;pi++) acc[nt][pi] = (f32x4){0.f,0.f,0.f,0.f};

  const float* fb = feat + (size_t)b*CHAN*HWSZ;

  for (int cc=0; cc<8; ++cc){
    const int c0 = cc*32;
    __syncthreads();
    for (int gi = t; gi < 1560; gi += 256){
      int xh = gi % 130;
      int q  = gi / 130;
      int cg = q & 3;
      int kh = q >> 2;
      int row = h + kh - 1;
      int xx  = xh - 1;
      bool ok = ((unsigned)row < 128u) & ((unsigned)xx < 128u);
      const float* src = fb + (size_t)(c0 + cg*8)*HWSZ + row*WW + xx;
      ushort8 u;
      #pragma unroll
      for (int j=0;j<8;j++){
        float v = ok ? src[(size_t)j*HWSZ] : 0.f;
        u[j] = f2bf(v);
      }
      *(ushort8*)&lds[(kh*132 + xh)*LDSX + cg*8] = u;
    }
    __syncthreads();

    const unsigned short* wbase = wr + ((size_t)cc*7*64 + l)*8;
    #pragma unroll 1
    for (int tap=0; tap<9; ++tap){
      const int kh = tap / 3;
      const int kw = tap - kh*3;
      bf16x8 a[7];
      #pragma unroll
      for (int nt=0; nt<7; nt++)
        a[nt] = *(const bf16x8*)(wbase + ((size_t)tap*8*7 + nt)*64*8);
      bf16x8 bfv[2];
      #pragma unroll
      for (int pi=0; pi<2; pi++){
        int xh = (w*2+pi)*16 + lx + kw;
        bfv[pi] = *(const bf16x8*)&lds[(kh*132 + xh)*LDSX + lg*8];
      }
      #pragma unroll
      for (int nt=0; nt<7; nt++)
        #pragma unroll
        for (int pi=0; pi<2; pi++)
          acc[nt][pi] = __builtin_amdgcn_mfma_f32_16x16x32_bf16(
              a[nt], bfv[pi], acc[nt][pi], 0, 0, 0);
    }
  }

  #pragma unroll
  for (int nt=0; nt<7; nt++){
    const int n0 = nt*16 + lg*4;
    #pragma unroll
    for (int pi=0; pi<2; pi++){
      const int xo = (w*2+pi)*16 + lx;
      #pragma unroll
      for (int r=0; r<4; r++){
        int n = n0 + r;
        if (n < NMASK)
          out_iam[((size_t)b*NMASK + n)*HWSZ + h*WW + xo] = acc[nt][pi][r] + cb[n];
      }
    }
  }
}

// ---------------- softmax row stats (max, 1/sumexp) ----------------
__global__ __launch_bounds__(256) void softmax_stats_kernel(
    const float* __restrict__ iam, float* __restrict__ rowmax, float* __restrict__ rowinv)
{
  const int row = blockIdx.x;
  const int t = threadIdx.x;
  const float* p = iam + (size_t)row*HWSZ;
  __shared__ float red[256];
  float m = -1e30f;
  for (int it=0; it<16; it++){
    float4 v = *(const float4*)&p[(it*256+t)*4];
    m = fmaxf(m, fmaxf(fmaxf(v.x,v.y), fmaxf(v.z,v.w)));
  }
  red[t] = m; __syncthreads();
  for (int s=128;s>0;s>>=1){ if (t<s) red[t]=fmaxf(red[t],red[t+s]); __syncthreads(); }
  m = red[0]; __syncthreads();
  float sum=0.f;
  for (int it=0; it<16; it++){
    float4 v = *(const float4*)&p[(it*256+t)*4];
    sum += expf(v.x-m)+expf(v.y-m)+expf(v.z-m)+expf(v.w-m);
  }
  red[t]=sum; __syncthreads();
  for (int s=128;s>0;s>>=1){ if (t<s) red[t]+=red[t+s]; __syncthreads(); }
  if (t==0){ rowmax[row]=m; rowinv[row]=1.0f/red[0]; }
}

// ---------------- einsum as MFMA (no LDS, no barriers) ----------------
__global__ __launch_bounds__(256) void einsum_mfma_kernel(
  const float* __restrict__ feat, const float* __restrict__ iam,
  const float* __restrict__ rowmax, const float* __restrict__ rowinv,
  float* __restrict__ partial)
{
  const int s = blockIdx.x;
  const int nsplit = gridDim.x;
  const int KC = HWSZ / nsplit;
  const int b = blockIdx.z;
  const int t = threadIdx.x;
  const int w = t >> 6;
  const int l = t & 63;
  const int lx = l & 15;
  const int lg = l >> 4;

  f32x4 acc[7][4];
  #pragma unroll
  for (int nt=0;nt<7;nt++)
    #pragma unroll
    for (int j=0;j<4;j++) acc[nt][j] = (f32x4){0.f,0.f,0.f,0.f};

  int   rown[7];
  float m_[7], r_[7];
  #pragma unroll
  for (int nt=0;nt<7;nt++){
    int row = nt*16 + lx;
    if (row >= NMASK) row = NMASK-1;
    rown[nt] = row;
    m_[nt] = rowmax[b*NMASK + row];
    r_[nt] = rowinv[b*NMASK + row];
  }

  const float* fb = feat + (size_t)b*CHAN*HWSZ;
  const float* ib = iam  + (size_t)b*NMASK*HWSZ;

  #pragma unroll 1
  for (int ks=0; ks<KC/32; ++ks){
    const int p0 = s*KC + ks*32 + lg*8;
    bf16x8 afr[7];
    #pragma unroll
    for (int nt=0;nt<7;nt++){
      const float* ap = ib + (size_t)rown[nt]*HWSZ + p0;
      float4 a0 = *(const float4*)ap;
      float4 a1 = *(const float4*)(ap+4);
      const float m = m_[nt], rv = r_[nt];
      ushort8 u;
      u[0]=f2bf(__expf(a0.x-m)*rv); u[1]=f2bf(__expf(a0.y-m)*rv);
      u[2]=f2bf(__expf(a0.z-m)*rv); u[3]=f2bf(__expf(a0.w-m)*rv);
      u[4]=f2bf(__expf(a1.x-m)*rv); u[5]=f2bf(__expf(a1.y-m)*rv);
      u[6]=f2bf(__expf(a1.z-m)*rv); u[7]=f2bf(__expf(a1.w-m)*rv);
      afr[nt] = *(bf16x8*)&u;
    }
    bf16x8 bfr[4];
    #pragma unroll
    for (int j=0;j<4;j++){
      const float* fp = fb + (size_t)(w*64 + j*16 + lx)*HWSZ + p0;
      float4 b0 = *(const float4*)fp;
      float4 b1 = *(const float4*)(fp+4);
      ushort8 u;
      u[0]=f2bf(b0.x); u[1]=f2bf(b0.y); u[2]=f2bf(b0.z); u[3]=f2bf(b0.w);
      u[4]=f2bf(b1.x); u[5]=f2bf(b1.y); u[6]=f2bf(b1.z); u[7]=f2bf(b1.w);
      bfr[j] = *(bf16x8*)&u;
    }
    #pragma unroll
    for (int nt=0;nt<7;nt++)
      #pragma unroll
      for (int j=0;j<4;j++)
        acc[nt][j] = __builtin_amdgcn_mfma_f32_16x16x32_bf16(
            afr[nt], bfr[j], acc[nt][j], 0, 0, 0);
  }

  #pragma unroll
  for (int nt=0;nt<7;nt++){
    #pragma unroll
    for (int j=0;j<4;j++){
      const int c = w*64 + j*16 + lx;
      #pragma unroll
      for (int r=0;r<4;r++){
        int n = nt*16 + lg*4 + r;
        if (n < NMASK)
          partial[(((size_t)b*nsplit + s)*NMASK + n)*CHAN + c] = acc[nt][j][r];
      }
    }
  }
}

// ---------------- reduce partials + fc + heads ----------------
__global__ __launch_bounds__(256) void fc_head_kernel(
  const float* __restrict__ partial, int nsplit,
  const float* __restrict__ fc_w, const float* __restrict__ fc_b,
  const float* __restrict__ cls_w, const float* __restrict__ cls_b,
  const float* __restrict__ mk_w, const float* __restrict__ mk_b,
  const float* __restrict__ obj_w, const float* __restrict__ obj_b,
  float* __restrict__ dout)
{
  const int n = blockIdx.x;
  const int b = blockIdx.y;
  const int t = threadIdx.x;
  __shared__ float xs[256];
  __shared__ float xr[256];
  __shared__ float red[256];
  float x = 0.f;
  for (int s=0;s<nsplit;s++)
    x += partial[(((size_t)b*nsplit+s)*NMASK + n)*CHAN + t];
  xs[t] = x;
  __syncthreads();
  float y = fc_b[t];
  const float* wr2 = fc_w + (size_t)t*CHAN;
  for (int k=0;k<CHAN;k+=4){
    float4 w4 = *(const float4*)&wr2[k];
    y = fmaf(xs[k],w4.x,y); y=fmaf(xs[k+1],w4.y,y);
    y = fmaf(xs[k+2],w4.z,y); y=fmaf(xs[k+3],w4.w,y);
  }
  y = fmaxf(y, 0.f);
  xr[t] = y;
  __syncthreads();
  if (t < KD){
    float ka = mk_b[t];
    const float* mr = mk_w + (size_t)t*CHAN;
    for (int k=0;k<CHAN;k+=4){
      float4 w4 = *(const float4*)&mr[k];
      ka = fmaf(xr[k],w4.x,ka); ka=fmaf(xr[k+1],w4.y,ka);
      ka = fmaf(xr[k+2],w4.z,ka); ka=fmaf(xr[k+3],w4.w,ka);
    }
    dout[OFF_KERNEL + ((size_t)b*NMASK + n)*KD + t] = ka;
  }
  red[t] = xr[t] * cls_w[t];
  __syncthreads();
  for (int s2=128;s2>0;s2>>=1){ if(t<s2) red[t]+=red[t+s2]; __syncthreads(); }
  if (t==0) dout[OFF_LOGITS + (size_t)b*NMASK + n] = red[0] + cls_b[0];
  __syncthreads();
  red[t] = xr[t] * obj_w[t];
  __syncthreads();
  for (int s2=128;s2>0;s2>>=1){ if(t<s2) red[t]+=red[t+s2]; __syncthreads(); }
  if (t==0) dout[OFF_SCORES + (size_t)b*NMASK + n] = red[0] + obj_b[0];
}

extern "C" void kernel_launch(void* const* d_in, const int* in_sizes, int n_in,
                              void* d_out, int out_size, void* d_ws, size_t ws_size,
                              hipStream_t stream)
{
  const float* feat   = (const float*)d_in[0];
  const float* conv_w = (const float*)d_in[1];
  const float* conv_b = (const float*)d_in[2];
  // d_in[3] = softmax_bias: scalar shift, softmax-invariant -> unused
  const float* fc_w   = (const float*)d_in[4];
  const float* fc_b   = (const float*)d_in[5];
  const float* cls_w  = (const float*)d_in[6];
  const float* cls_b  = (const float*)d_in[7];
  const float* mk_w   = (const float*)d_in[8];
  const float* mk_b   = (const float*)d_in[9];
  const float* obj_w  = (const float*)d_in[10];
  const float* obj_b  = (const float*)d_in[11];
  float* dout = (float*)d_out;
  float* iam  = dout + OFF_IAM;

  const size_t statb = 1600*sizeof(float);                 // 6400
  const size_t wrb   = (size_t)9*8*7*64*8*2;               // 516096
  const size_t feathb = (size_t)BATCH*32*HWSZ*8*2;         // 67,108,864

  float* rowmax  = (float*)d_ws;
  float* rowinv  = rowmax + 800;
  unsigned short* wr = (unsigned short*)((char*)d_ws + statb);
  char* shared_region = (char*)d_ws + statb + wrb;

  wpack_kernel<<<dim3((9*8*7*64*8 + 255)/256), 256, 0, stream>>>(conv_w, wr);

  if (ws_size >= statb + wrb + feathb + 1024){
    // mode A: prepass + no-barrier conv; partial aliases feat_h (disjoint lifetimes)
    unsigned short* feath = (unsigned short*)shared_region;
    float* partial = (float*)shared_region;
    const int ksplit = 64;   // 52.4 MB < 67.1 MB feat_h region
    prepack_feat_kernel<<<dim3(8,32,8), 256, 0, stream>>>(feat, feath);
    conv_mfma3_kernel<<<dim3(64, 8), 256, 0, stream>>>(feath, wr, conv_b, iam);
    softmax_stats_kernel<<<dim3(800), 256, 0, stream>>>(iam, rowmax, rowinv);
    einsum_mfma_kernel<<<dim3(ksplit, 1, 8), 256, 0, stream>>>(feat, iam, rowmax, rowinv, partial);
    fc_head_kernel<<<dim3(NMASK,BATCH), 256, 0, stream>>>(partial, ksplit, fc_w, fc_b,
        cls_w, cls_b, mk_w, mk_b, obj_w, obj_b, dout);
  } else {
    // mode B: round-4 path (no prepass)
    float* partial = (float*)shared_region;
    int ksplit = 16;
    if (ws_size >= statb + wrb + (size_t)64*BATCH*NMASK*CHAN*4) ksplit = 64;
    else if (ws_size >= statb + wrb + (size_t)32*BATCH*NMASK*CHAN*4) ksplit = 32;
    conv_mfma_kernel<<<dim3(128, 8), 256, 0, stream>>>(feat, wr, conv_b, iam);
    softmax_stats_kernel<<<dim3(800), 256, 0, stream>>>(iam, rowmax, rowinv);
    einsum_mfma_kernel<<<dim3(ksplit, 1, 8), 256, 0, stream>>>(feat, iam, rowmax, rowinv, partial);
    fc_head_kernel<<<dim3(NMASK,BATCH), 256, 0, stream>>>(partial, ksplit, fc_w, fc_b,
        cls_w, cls_b, mk_w, mk_b, obj_w, obj_b, dout);
  }
}

// Round 7
// 239.077 us; speedup vs baseline: 1.4960x; 1.1197x over previous
//
#include <hip/hip_runtime.h>
#include <math.h>

#define BATCH 8
#define CHAN 256
#define HH 128
#define WW 128
#define NMASK 100
#define HWSZ (HH*WW)
#define KD 128

// d_out layout: [logits 800][kernel 102400][scores 800][iam 13107200]
#define OFF_LOGITS 0
#define OFF_KERNEL 800
#define OFF_SCORES (800 + 800*KD)
#define OFF_IAM    (OFF_SCORES + 800)

typedef __attribute__((ext_vector_type(8))) short bf16x8;
typedef __attribute__((ext_vector_type(8))) unsigned short ushort8;
typedef __attribute__((ext_vector_type(4))) float f32x4;

#define WCHUNK (9*7*64*8)   // ushorts per cc-chunk of packed weights (64.5 KB)

__device__ __forceinline__ unsigned short f2bf(float f){
  unsigned int u = __float_as_uint(f);
  u += 0x7fffu + ((u >> 16) & 1u);
  return (unsigned short)(u >> 16);
}

// ---------------- weight pre-pack, chunk-contiguous layout ----------------
// wr[(((cc*9+tap)*7+nt)*64+l)*8+j] = bf16(W[n][c][kh][kw])
//   n = nt*16+(l&15), c = cc*32+(l>>4)*8+j, tap = kh*3+kw; n>=100 -> 0
__global__ __launch_bounds__(256) void wpack_kernel(
    const float* __restrict__ cw, unsigned short* __restrict__ wr)
{
  int i = blockIdx.x*256 + threadIdx.x;
  if (i >= 8*9*7*64*8) return;
  int j = i & 7;
  int l = (i >> 3) & 63;
  int rest = i >> 9;
  int nt = rest % 7;
  int tc = rest / 7;
  int tap = tc % 9;
  int cc  = tc / 9;
  int n = nt*16 + (l & 15);
  int c = cc*32 + (l >> 4)*8 + j;
  float v = 0.f;
  if (n < NMASK) v = cw[((size_t)n*CHAN + c)*9 + tap];
  wr[i] = f2bf(v);
}

// ---------------- feature layout prepass: fp32 [b][c][p] -> bf16 [b][cg][p][c8] ----
__global__ __launch_bounds__(256) void prepack_feat_kernel(
    const float* __restrict__ feat, unsigned short* __restrict__ feath)
{
  const int b  = blockIdx.z;
  const int cg = blockIdx.y;
  const int t  = threadIdx.x;
  __shared__ unsigned short lt[8*264];
  const int cl = t >> 5;           // 0..7
  const int po = (t & 31)*8;       // 0..248
  for (int st=0; st<8; ++st){
    const int P0 = blockIdx.x*2048 + st*256;
    const float* src = feat + ((size_t)(b*CHAN + cg*8 + cl))*HWSZ + P0 + po;
    float4 a0 = *(const float4*)src;
    float4 a1 = *(const float4*)(src+4);
    ushort8 u;
    u[0]=f2bf(a0.x); u[1]=f2bf(a0.y); u[2]=f2bf(a0.z); u[3]=f2bf(a0.w);
    u[4]=f2bf(a1.x); u[5]=f2bf(a1.y); u[6]=f2bf(a1.z); u[7]=f2bf(a1.w);
    *(ushort8*)&lt[cl*264 + po] = u;
    __syncthreads();
    ushort8 v;
    #pragma unroll
    for (int c=0;c<8;c++) v[c] = lt[c*264 + t];
    *(ushort8*)&feath[(((size_t)b*32 + cg)*HWSZ + P0 + t)*8] = v;
    __syncthreads();
  }
}

// ---------------- conv v4: A-slab in LDS (shared by 4 waves), B direct ----------
// grid (64 h-pairs, 8 b), 4 waves. Wave w owns x-tiles {2w,2w+1} x 2 rows x 7 nt.
__global__ __launch_bounds__(256,2) void conv_mfma4_kernel(
    const unsigned short* __restrict__ feath, const unsigned short* __restrict__ wr,
    const float* __restrict__ cb, float* __restrict__ out_iam)
{
  const int h0 = blockIdx.x*2;
  const int b  = blockIdx.y;
  const int t  = threadIdx.x;
  const int w  = t >> 6;
  const int l  = t & 63;
  const int lx = l & 15;
  const int lg = l >> 4;

  __shared__ unsigned short lA[WCHUNK];   // 64.5 KB, one weight chunk

  f32x4 acc[7][2][2];   // [nt][row][pi]
  #pragma unroll
  for (int nt=0;nt<7;nt++)
    #pragma unroll
    for (int r=0;r<2;r++)
      #pragma unroll
      for (int pi=0;pi<2;pi++) acc[nt][r][pi] = (f32x4){0.f,0.f,0.f,0.f};

  const unsigned short* fb = feath + ((size_t)b*32 + lg)*HWSZ*8;
  const int xb0 = (w*2+0)*16 + lx - 1;
  const int xb1 = (w*2+1)*16 + lx - 1;

  #pragma unroll 1
  for (int cc=0; cc<8; ++cc){
    __syncthreads();   // prior chunk's LDS reads complete
    {
      // stage chunk cc: 63 frag-groups of 64 lanes x 16B; group g2 = it*4 + w
      const unsigned short* src = wr + (size_t)cc*WCHUNK;
      #pragma unroll
      for (int it=0; it<16; ++it){
        int g2 = it*4 + w;
        if (g2 < 63){
          ushort8 v = *(const ushort8*)(src + ((size_t)g2*64 + l)*8);
          *(ushort8*)&lA[((size_t)g2*64 + l)*8] = v;
        }
      }
    }
    __syncthreads();   // slab visible to all waves

    const unsigned short* fcc = fb + (size_t)cc*4*HWSZ*8;
    #pragma unroll
    for (int tap=0; tap<9; ++tap){
      const int kh = tap/3, kw = tap - 3*(tap/3);
      bf16x8 a[7];
      #pragma unroll
      for (int nt=0;nt<7;nt++)
        a[nt] = *(const bf16x8*)&lA[(((size_t)tap*7+nt)*64 + l)*8];
      bf16x8 bv[2][2];
      #pragma unroll
      for (int r=0;r<2;r++){
        const int hr = h0 + r + kh - 1;
        const bool rv = (unsigned)hr < 128u;
        const int hc = rv ? hr : 0;
        #pragma unroll
        for (int pi=0;pi<2;pi++){
          const int X = (pi ? xb1 : xb0) + kw;
          const bool xv = (unsigned)X < 128u;
          const int Xc = xv ? X : 0;
          bf16x8 v = *(const bf16x8*)&fcc[((size_t)hc*WW + Xc)*8];
          bv[r][pi] = (rv && xv) ? v : (bf16x8)(short)0;
        }
      }
      #pragma unroll
      for (int nt=0;nt<7;nt++)
        #pragma unroll
        for (int r=0;r<2;r++)
          #pragma unroll
          for (int pi=0;pi<2;pi++)
            acc[nt][r][pi] = __builtin_amdgcn_mfma_f32_16x16x32_bf16(
                a[nt], bv[r][pi], acc[nt][r][pi], 0, 0, 0);
    }
  }

  // D: col(x) = lane&15, row(mask) = (lane>>4)*4 + q
  #pragma unroll
  for (int nt=0; nt<7; nt++){
    const int n0 = nt*16 + lg*4;
    #pragma unroll
    for (int r=0; r<2; r++){
      #pragma unroll
      for (int pi=0; pi<2; pi++){
        const int xo = (w*2+pi)*16 + lx;
        #pragma unroll
        for (int q=0; q<4; q++){
          int n = n0 + q;
          if (n < NMASK)
            out_iam[((size_t)b*NMASK + n)*HWSZ + (h0+r)*WW + xo] = acc[nt][r][pi][q] + cb[n];
        }
      }
    }
  }
}

// ---------------- conv v1 (fallback for small ws: fp32 staging via LDS) ----------
#define LDSX 40
__global__ __launch_bounds__(256) void conv_mfma_kernel(
    const float* __restrict__ feat, const unsigned short* __restrict__ wr,
    const float* __restrict__ cb, float* __restrict__ out_iam)
{
  const int h = blockIdx.x;
  const int b = blockIdx.y;
  const int t = threadIdx.x;
  const int w = t >> 6;
  const int l = t & 63;
  const int lx = l & 15;
  const int lg = l >> 4;

  __shared__ unsigned short lds[3*132*LDSX];

  f32x4 acc[7][2];
  #pragma unroll
  for (int nt=0;nt<7;nt++)
    #pragma unroll
    for (int pi=0;pi<2;pi++) acc[nt][pi] = (f32x4){0.f,0.f,0.f,0.f};

  const float* fb = feat + (size_t)b*CHAN*HWSZ;

  for (int cc=0; cc<8; ++cc){
    const int c0 = cc*32;
    __syncthreads();
    for (int gi = t; gi < 1560; gi += 256){
      int xh = gi % 130;
      int q  = gi / 130;
      int cg = q & 3;
      int kh = q >> 2;
      int row = h + kh - 1;
      int xx  = xh - 1;
      bool ok = ((unsigned)row < 128u) & ((unsigned)xx < 128u);
      const float* src = fb + (size_t)(c0 + cg*8)*HWSZ + row*WW + xx;
      ushort8 u;
      #pragma unroll
      for (int j=0;j<8;j++){
        float v = ok ? src[(size_t)j*HWSZ] : 0.f;
        u[j] = f2bf(v);
      }
      *(ushort8*)&lds[(kh*132 + xh)*LDSX + cg*8] = u;
    }
    __syncthreads();

    const unsigned short* wbase = wr + ((size_t)cc*9*7*64 + l)*8;
    #pragma unroll 1
    for (int tap=0; tap<9; ++tap){
      const int kh = tap / 3;
      const int kw = tap - kh*3;
      bf16x8 a[7];
      #pragma unroll
      for (int nt=0; nt<7; nt++)
        a[nt] = *(const bf16x8*)(wbase + ((size_t)(tap*7 + nt))*64*8);
      bf16x8 bfv[2];
      #pragma unroll
      for (int pi=0; pi<2; pi++){
        int xh = (w*2+pi)*16 + lx + kw;
        bfv[pi] = *(const bf16x8*)&lds[(kh*132 + xh)*LDSX + lg*8];
      }
      #pragma unroll
      for (int nt=0; nt<7; nt++)
        #pragma unroll
        for (int pi=0; pi<2; pi++)
          acc[nt][pi] = __builtin_amdgcn_mfma_f32_16x16x32_bf16(
              a[nt], bfv[pi], acc[nt][pi], 0, 0, 0);
    }
  }

  #pragma unroll
  for (int nt=0; nt<7; nt++){
    const int n0 = nt*16 + lg*4;
    #pragma unroll
    for (int pi=0; pi<2; pi++){
      const int xo = (w*2+pi)*16 + lx;
      #pragma unroll
      for (int r=0; r<4; r++){
        int n = n0 + r;
        if (n < NMASK)
          out_iam[((size_t)b*NMASK + n)*HWSZ + h*WW + xo] = acc[nt][pi][r] + cb[n];
      }
    }
  }
}

// ---------------- softmax row stats (max, 1/sumexp) ----------------
__global__ __launch_bounds__(256) void softmax_stats_kernel(
    const float* __restrict__ iam, float* __restrict__ rowmax, float* __restrict__ rowinv)
{
  const int row = blockIdx.x;
  const int t = threadIdx.x;
  const float* p = iam + (size_t)row*HWSZ;
  __shared__ float red[256];
  float m = -1e30f;
  for (int it=0; it<16; it++){
    float4 v = *(const float4*)&p[(it*256+t)*4];
    m = fmaxf(m, fmaxf(fmaxf(v.x,v.y), fmaxf(v.z,v.w)));
  }
  red[t] = m; __syncthreads();
  for (int s=128;s>0;s>>=1){ if (t<s) red[t]=fmaxf(red[t],red[t+s]); __syncthreads(); }
  m = red[0]; __syncthreads();
  float sum=0.f;
  for (int it=0; it<16; it++){
    float4 v = *(const float4*)&p[(it*256+t)*4];
    sum += expf(v.x-m)+expf(v.y-m)+expf(v.z-m)+expf(v.w-m);
  }
  red[t]=sum; __syncthreads();
  for (int s=128;s>0;s>>=1){ if (t<s) red[t]+=red[t+s]; __syncthreads(); }
  if (t==0){ rowmax[row]=m; rowinv[row]=1.0f/red[0]; }
}

// ---------------- einsum as MFMA (no LDS, no barriers) ----------------
__global__ __launch_bounds__(256) void einsum_mfma_kernel(
  const float* __restrict__ feat, const float* __restrict__ iam,
  const float* __restrict__ rowmax, const float* __restrict__ rowinv,
  float* __restrict__ partial)
{
  const int s = blockIdx.x;
  const int nsplit = gridDim.x;
  const int KC = HWSZ / nsplit;
  const int b = blockIdx.z;
  const int t = threadIdx.x;
  const int w = t >> 6;
  const int l = t & 63;
  const int lx = l & 15;
  const int lg = l >> 4;

  f32x4 acc[7][4];
  #pragma unroll
  for (int nt=0;nt<7;nt++)
    #pragma unroll
    for (int j=0;j<4;j++) acc[nt][j] = (f32x4){0.f,0.f,0.f,0.f};

  int   rown[7];
  float m_[7], r_[7];
  #pragma unroll
  for (int nt=0;nt<7;nt++){
    int row = nt*16 + lx;
    if (row >= NMASK) row = NMASK-1;
    rown[nt] = row;
    m_[nt] = rowmax[b*NMASK + row];
    r_[nt] = rowinv[b*NMASK + row];
  }

  const float* fb = feat + (size_t)b*CHAN*HWSZ;
  const float* ib = iam  + (size_t)b*NMASK*HWSZ;

  #pragma unroll 1
  for (int ks=0; ks<KC/32; ++ks){
    const int p0 = s*KC + ks*32 + lg*8;
    bf16x8 afr[7];
    #pragma unroll
    for (int nt=0;nt<7;nt++){
      const float* ap = ib + (size_t)rown[nt]*HWSZ + p0;
      float4 a0 = *(const float4*)ap;
      float4 a1 = *(const float4*)(ap+4);
      const float m = m_[nt], rv = r_[nt];
      ushort8 u;
      u[0]=f2bf(__expf(a0.x-m)*rv); u[1]=f2bf(__expf(a0.y-m)*rv);
      u[2]=f2bf(__expf(a0.z-m)*rv); u[3]=f2bf(__expf(a0.w-m)*rv);
      u[4]=f2bf(__expf(a1.x-m)*rv); u[5]=f2bf(__expf(a1.y-m)*rv);
      u[6]=f2bf(__expf(a1.z-m)*rv); u[7]=f2bf(__expf(a1.w-m)*rv);
      afr[nt] = *(bf16x8*)&u;
    }
    bf16x8 bfr[4];
    #pragma unroll
    for (int j=0;j<4;j++){
      const float* fp = fb + (size_t)(w*64 + j*16 + lx)*HWSZ + p0;
      float4 b0 = *(const float4*)fp;
      float4 b1 = *(const float4*)(fp+4);
      ushort8 u;
      u[0]=f2bf(b0.x); u[1]=f2bf(b0.y); u[2]=f2bf(b0.z); u[3]=f2bf(b0.w);
      u[4]=f2bf(b1.x); u[5]=f2bf(b1.y); u[6]=f2bf(b1.z); u[7]=f2bf(b1.w);
      bfr[j] = *(bf16x8*)&u;
    }
    #pragma unroll
    for (int nt=0;nt<7;nt++)
      #pragma unroll
      for (int j=0;j<4;j++)
        acc[nt][j] = __builtin_amdgcn_mfma_f32_16x16x32_bf16(
            afr[nt], bfr[j], acc[nt][j], 0, 0, 0);
  }

  #pragma unroll
  for (int nt=0;nt<7;nt++){
    #pragma unroll
    for (int j=0;j<4;j++){
      const int c = w*64 + j*16 + lx;
      #pragma unroll
      for (int r=0;r<4;r++){
        int n = nt*16 + lg*4 + r;
        if (n < NMASK)
          partial[(((size_t)b*nsplit + s)*NMASK + n)*CHAN + c] = acc[nt][j][r];
      }
    }
  }
}

// ---------------- reduce partials + fc + heads ----------------
__global__ __launch_bounds__(256) void fc_head_kernel(
  const float* __restrict__ partial, int nsplit,
  const float* __restrict__ fc_w, const float* __restrict__ fc_b,
  const float* __restrict__ cls_w, const float* __restrict__ cls_b,
  const float* __restrict__ mk_w, const float* __restrict__ mk_b,
  const float* __restrict__ obj_w, const float* __restrict__ obj_b,
  float* __restrict__ dout)
{
  const int n = blockIdx.x;
  const int b = blockIdx.y;
  const int t = threadIdx.x;
  __shared__ float xs[256];
  __shared__ float xr[256];
  __shared__ float red[256];
  float x = 0.f;
  for (int s=0;s<nsplit;s++)
    x += partial[(((size_t)b*nsplit+s)*NMASK + n)*CHAN + t];
  xs[t] = x;
  __syncthreads();
  float y = fc_b[t];
  const float* wr2 = fc_w + (size_t)t*CHAN;
  for (int k=0;k<CHAN;k+=4){
    float4 w4 = *(const float4*)&wr2[k];
    y = fmaf(xs[k],w4.x,y); y=fmaf(xs[k+1],w4.y,y);
    y = fmaf(xs[k+2],w4.z,y); y=fmaf(xs[k+3],w4.w,y);
  }
  y = fmaxf(y, 0.f);
  xr[t] = y;
  __syncthreads();
  if (t < KD){
    float ka = mk_b[t];
    const float* mr = mk_w + (size_t)t*CHAN;
    for (int k=0;k<CHAN;k+=4){
      float4 w4 = *(const float4*)&mr[k];
      ka = fmaf(xr[k],w4.x,ka); ka=fmaf(xr[k+1],w4.y,ka);
      ka = fmaf(xr[k+2],w4.z,ka); ka=fmaf(xr[k+3],w4.w,ka);
    }
    dout[OFF_KERNEL + ((size_t)b*NMASK + n)*KD + t] = ka;
  }
  red[t] = xr[t] * cls_w[t];
  __syncthreads();
  for (int s2=128;s2>0;s2>>=1){ if(t<s2) red[t]+=red[t+s2]; __syncthreads(); }
  if (t==0) dout[OFF_LOGITS + (size_t)b*NMASK + n] = red[0] + cls_b[0];
  __syncthreads();
  red[t] = xr[t] * obj_w[t];
  __syncthreads();
  for (int s2=128;s2>0;s2>>=1){ if(t<s2) red[t]+=red[t+s2]; __syncthreads(); }
  if (t==0) dout[OFF_SCORES + (size_t)b*NMASK + n] = red[0] + obj_b[0];
}

extern "C" void kernel_launch(void* const* d_in, const int* in_sizes, int n_in,
                              void* d_out, int out_size, void* d_ws, size_t ws_size,
                              hipStream_t stream)
{
  const float* feat   = (const float*)d_in[0];
  const float* conv_w = (const float*)d_in[1];
  const float* conv_b = (const float*)d_in[2];
  // d_in[3] = softmax_bias: scalar shift, softmax-invariant -> unused
  const float* fc_w   = (const float*)d_in[4];
  const float* fc_b   = (const float*)d_in[5];
  const float* cls_w  = (const float*)d_in[6];
  const float* cls_b  = (const float*)d_in[7];
  const float* mk_w   = (const float*)d_in[8];
  const float* mk_b   = (const float*)d_in[9];
  const float* obj_w  = (const float*)d_in[10];
  const float* obj_b  = (const float*)d_in[11];
  float* dout = (float*)d_out;
  float* iam  = dout + OFF_IAM;

  const size_t statb = 1600*sizeof(float);                 // 6400
  const size_t wrb   = (size_t)8*WCHUNK*2;                 // 516096
  const size_t feathb = (size_t)BATCH*32*HWSZ*8*2;         // 67,108,864

  float* rowmax  = (float*)d_ws;
  float* rowinv  = rowmax + 800;
  unsigned short* wr = (unsigned short*)((char*)d_ws + statb);
  char* shared_region = (char*)d_ws + statb + wrb;

  wpack_kernel<<<dim3((8*WCHUNK + 255)/256), 256, 0, stream>>>(conv_w, wr);

  if (ws_size >= statb + wrb + feathb + 1024){
    // mode A: prepass + A-LDS conv; partial aliases feat_h (disjoint lifetimes)
    unsigned short* feath = (unsigned short*)shared_region;
    float* partial = (float*)shared_region;
    const int ksplit = 64;   // 52.4 MB < 67.1 MB feat_h region
    prepack_feat_kernel<<<dim3(8,32,8), 256, 0, stream>>>(feat, feath);
    conv_mfma4_kernel<<<dim3(64, 8), 256, 0, stream>>>(feath, wr, conv_b, iam);
    softmax_stats_kernel<<<dim3(800), 256, 0, stream>>>(iam, rowmax, rowinv);
    einsum_mfma_kernel<<<dim3(ksplit, 1, 8), 256, 0, stream>>>(feat, iam, rowmax, rowinv, partial);
    fc_head_kernel<<<dim3(NMASK,BATCH), 256, 0, stream>>>(partial, ksplit, fc_w, fc_b,
        cls_w, cls_b, mk_w, mk_b, obj_w, obj_b, dout);
  } else {
    // mode B: no-prepass path
    float* partial = (float*)shared_region;
    int ksplit = 16;
    if (ws_size >= statb + wrb + (size_t)64*BATCH*NMASK*CHAN*4) ksplit = 64;
    else if (ws_size >= statb + wrb + (size_t)32*BATCH*NMASK*CHAN*4) ksplit = 32;
    conv_mfma_kernel<<<dim3(128, 8), 256, 0, stream>>>(feat, wr, conv_b, iam);
    softmax_stats_kernel<<<dim3(800), 256, 0, stream>>>(iam, rowmax, rowinv);
    einsum_mfma_kernel<<<dim3(ksplit, 1, 8), 256, 0, stream>>>(feat, iam, rowmax, rowinv, partial);
    fc_head_kernel<<<dim3(NMASK,BATCH), 256, 0, stream>>>(partial, ksplit, fc_w, fc_b,
        cls_w, cls_b, mk_w, mk_b, obj_w, obj_b, dout);
  }
}